// Round 1
// baseline (701.935 us; speedup 1.0000x reference)
//
#include <hip/hip_runtime.h>
#include <stdint.h>

// PackBits: out[w] = packed sign bits of x[32w .. 32w+31].
// Bit mapping (np.packbits MSB-first + little-endian uint32 view):
//   element p -> bit q = 8*(p>>3) + 7 - (p&7)
// Natural-order word nat (bit p = signbit(x[32w+p])) then
//   out = bswap(brev(nat))   — verified correct (absmax 0) in prior rounds.
//
// R3: persistent grid. 2048 blocks x 256 threads (= 8192 waves, the full
// 32-wave/CU residency at 256 CUs), grid-stride loop unrolled x8 with all
// 8 independent uint4 loads issued before the pack/butterfly phase.
// Rationale: R2 issued ONE 16B load per thread across 131072 short-lived
// workgroups -> 1-deep memory pipeline per wave + block-churn, ~1.7 TB/s.
// 8-deep ILP + 64x launch amortization should reach HBM read ceiling.
// Per-instruction coalescing preserved: lane i loads uint4 at base + i.

#define THREADS 256
#define BLOCKS  2048
#define UNROLL  8

__global__ __launch_bounds__(THREADS) void PackBits_61289183314094_kernel(
    const uint4* __restrict__ x4, uint32_t* __restrict__ out, int n4) {
  const int nthreads = gridDim.x * blockDim.x;
  const int lane = threadIdx.x & 63;
  const int sub = lane & 7;  // position of this lane's nibble in the word

  int i = blockIdx.x * blockDim.x + threadIdx.x;

  // Main loop: 8 independent loads in flight, then 8 pack+butterfly rounds.
  for (; i + (UNROLL - 1) * nthreads < n4; i += UNROLL * nthreads) {
    uint4 v[UNROLL];
#pragma unroll
    for (int k = 0; k < UNROLL; ++k) v[k] = x4[i + k * nthreads];
#pragma unroll
    for (int k = 0; k < UNROLL; ++k) {
      // nibble: bit c = signbit of float c (natural order within nibble)
      uint32_t nib = (v[k].x >> 31) | ((v[k].y >> 31) << 1) |
                     ((v[k].z >> 31) << 2) | ((v[k].w >> 31) << 3);
      uint32_t part = nib << (4 * sub);
      // OR-butterfly across the 8-lane group
      part |= __shfl_xor(part, 1);
      part |= __shfl_xor(part, 2);
      part |= __shfl_xor(part, 4);
      if (sub == 0) {
        out[(i + k * nthreads) >> 3] = __builtin_bswap32(__brev(part));
      }
    }
  }

  // Tail (empty for N = 2^27, kept for generality; n4 is a multiple of 8
  // since N is a multiple of 32, so every 8-lane group is always full).
  for (; i < n4; i += nthreads) {
    uint4 v = x4[i];
    uint32_t nib = (v.x >> 31) | ((v.y >> 31) << 1) | ((v.z >> 31) << 2) |
                   ((v.w >> 31) << 3);
    uint32_t part = nib << (4 * sub);
    part |= __shfl_xor(part, 1);
    part |= __shfl_xor(part, 2);
    part |= __shfl_xor(part, 4);
    if (sub == 0) out[i >> 3] = __builtin_bswap32(__brev(part));
  }
}

extern "C" void kernel_launch(void* const* d_in, const int* in_sizes, int n_in,
                              void* d_out, int out_size, void* d_ws, size_t ws_size,
                              hipStream_t stream) {
  const uint4* x4 = (const uint4*)d_in[0];
  uint32_t* out = (uint32_t*)d_out;
  int n = in_sizes[0];   // 2^27 floats
  int n4 = n / 4;        // 2^25 uint4 elements

  int blocks = (n4 + THREADS - 1) / THREADS;
  if (blocks > BLOCKS) blocks = BLOCKS;
  PackBits_61289183314094_kernel<<<blocks, THREADS, 0, stream>>>(x4, out, n4);
}

// Round 3
// 646.250 us; speedup vs baseline: 1.0862x; 1.0862x over previous
//
#include <hip/hip_runtime.h>
#include <stdint.h>

// PackBits: out[w] = packed sign bits of x[32w .. 32w+31].
// Bit mapping (np.packbits MSB-first + little-endian uint32 view):
//   element p -> bit q = 8*(p>>3) + 7 - (p&7)
// Natural-order word nat (bit p = signbit(x[32w+p])), then
//   out = bswap(brev(nat))   — verified correct (absmax 0) in all rounds.
//
// R5 = R4 with the compile fix: __builtin_nontemporal_load requires a NATIVE
// vector type (HIP's uint4 is a class). Use ext_vector_type(4) of uint32_t.
//
// Design (R4 rationale):
//  - R2 (1 load/thread, 131072 blocks) = 656 us total: block churn, but each
//    wave reads one contiguous 1 KiB (good page locality).
//  - R3 (2048 persistent blocks, 8 MiB-strided loads) = 702 us: REGRESSION.
//    Each wave held 8 loads to pages 8 MiB apart -> ~256 live pages/CU,
//    TLB/page thrash. Strided multi-stream is the enemy, not churn alone.
//  - R5 keeps both good properties: block tile is CONTIGUOUS (thread t loads
//    tile + t*16 + j*4096; all 8 loads inside one 32 KiB region ~ 1 page),
//    per-instruction coalescing intact (lane i -> consecutive 16 B), and
//    16384 blocks amortize launch 8x vs R2 with zero tail.
//  - Nontemporal load/store: input is read-once with full-line consumption
//    (no reuse to lose) -> skip cache allocation, avoid evicting the poison
//    fill's dirty L3 lines during our read.

typedef uint32_t uvec4 __attribute__((ext_vector_type(4)));

#define THREADS 256
#define UNROLL  8
#define TILE    (THREADS * UNROLL)  // uint4 elems per block tile = 2048 (32 KiB)

__global__ __launch_bounds__(THREADS) void PackBits_61289183314094_kernel(
    const uvec4* __restrict__ x4, uint32_t* __restrict__ out, int n4) {
  const int t = threadIdx.x;
  const int sub = t & 7;  // nibble slot within this 8-lane group's word
  const int base = blockIdx.x * TILE + t;

  if (base + (UNROLL - 1) * THREADS < n4) {
    // Full tile: issue all 8 independent 16 B loads, then pack.
    uvec4 v[UNROLL];
#pragma unroll
    for (int j = 0; j < UNROLL; ++j)
      v[j] = __builtin_nontemporal_load(&x4[base + j * THREADS]);
#pragma unroll
    for (int j = 0; j < UNROLL; ++j) {
      uint32_t nib = (v[j].x >> 31) | ((v[j].y >> 31) << 1) |
                     ((v[j].z >> 31) << 2) | ((v[j].w >> 31) << 3);
      uint32_t part = nib << (4 * sub);
      // OR-butterfly across the 8-lane group
      part |= __shfl_xor(part, 1);
      part |= __shfl_xor(part, 2);
      part |= __shfl_xor(part, 4);
      if (sub == 0) {
        uint32_t w = __builtin_bswap32(__brev(part));
        __builtin_nontemporal_store(w, &out[(base + j * THREADS) >> 3]);
      }
    }
  } else {
    // Tail tile. n is a multiple of 32 -> n4 multiple of 8, so the bounds
    // test is uniform across each 8-lane group: the butterfly always runs
    // with all 8 lanes of a group active.
    for (int j = 0; j < UNROLL; ++j) {
      const int idx = base + j * THREADS;
      if (idx < n4) {
        uvec4 v = x4[idx];
        uint32_t nib = (v.x >> 31) | ((v.y >> 31) << 1) | ((v.z >> 31) << 2) |
                       ((v.w >> 31) << 3);
        uint32_t part = nib << (4 * sub);
        part |= __shfl_xor(part, 1);
        part |= __shfl_xor(part, 2);
        part |= __shfl_xor(part, 4);
        if (sub == 0) out[idx >> 3] = __builtin_bswap32(__brev(part));
      }
    }
  }
}

extern "C" void kernel_launch(void* const* d_in, const int* in_sizes, int n_in,
                              void* d_out, int out_size, void* d_ws, size_t ws_size,
                              hipStream_t stream) {
  const uvec4* x4 = (const uvec4*)d_in[0];
  uint32_t* out = (uint32_t*)d_out;
  int n = in_sizes[0];   // 2^27 floats
  int n4 = n / 4;        // 2^25 uint4 elements

  int blocks = (n4 + TILE - 1) / TILE;  // 16384 for N = 2^27
  PackBits_61289183314094_kernel<<<blocks, THREADS, 0, stream>>>(x4, out, n4);
}